// Round 1
// baseline (191.534 us; speedup 1.0000x reference)
//
#include <hip/hip_runtime.h>
#include <math.h>

#define IMG_H 512
#define IMG_W 512
#define NIMG 64
#define TH 64        // output rows per block
#define TCOLS 256    // output cols per block (== blockDim.x)
#define HALO 5
#define KSIZE 11
#define LROW (TCOLS + 2*HALO)   // 266 staged input cols per row

// Each block: 256 threads, each owns one output column of a 256-col strip.
// Streams 74 input rows (64 outputs + 2*5 halo, padded to 77 = 7*11 for the
// static ring indexing). Per row: stage row into LDS (double-buffered),
// horizontal 11-tap conv of {p, g, p^2, g^2, p*g} from LDS, push into an
// 11-deep register ring, then vertical 11-tap conv + SSIM formula once the
// ring is full. One __syncthreads per row.
__global__ __launch_bounds__(256, 4)
void ssim_main(const float* __restrict__ pred, const float* __restrict__ gt,
               float* __restrict__ partial) {
    __shared__ float sp[2][LROW];
    __shared__ float sg[2][LROW];
    __shared__ float wsum[4];

    const int tid = threadIdx.x;
    const int bid = blockIdx.x;
    const int img = bid >> 4;          // 16 blocks per image
    const int rem = bid & 15;
    const int c0  = (rem & 1) * TCOLS; // 2 column strips
    const int r0  = (rem >> 1) * TH;   // 8 row chunks

    // Gaussian window (matches reference: sigma = 11/6, normalized), fp32.
    float wgt[KSIZE];
    {
        const float sigma = 11.0f / 6.0f;
        float s = 0.f;
        #pragma unroll
        for (int i = 0; i < KSIZE; ++i) {
            float d = (float)(i - 5);
            wgt[i] = expf(-d * d / (2.f * sigma * sigma));
            s += wgt[i];
        }
        float inv = 1.f / s;
        #pragma unroll
        for (int i = 0; i < KSIZE; ++i) wgt[i] *= inv;
    }

    const float* pimg = pred + (size_t)img * IMG_H * IMG_W;
    const float* gimg = gt   + (size_t)img * IMG_H * IMG_W;

    const int  cs0   = c0 - HALO + tid;      // staged col for lane (first elem)
    const int  cs1   = cs0 + 256;            // tail elem (lanes 0..9)
    const bool has2  = tid < (LROW - 256);
    const bool c0ok  = (cs0 >= 0) && (cs0 < IMG_W);
    const bool c1ok  = has2 && (cs1 < IMG_W);

    float stp0, stp1, stg0, stg1;            // staged regs for next row

    auto load_row = [&](int r, float& p0, float& p1, float& g0, float& g1) {
        const bool rok = (r >= 0) && (r < IMG_H);
        const float* prow = pimg + (size_t)r * IMG_W;
        const float* grow = gimg + (size_t)r * IMG_W;
        p0 = (rok && c0ok) ? prow[cs0] : 0.f;
        g0 = (rok && c0ok) ? grow[cs0] : 0.f;
        p1 = (rok && c1ok) ? prow[cs1] : 0.f;
        g1 = (rok && c1ok) ? grow[cs1] : 0.f;
    };

    const int r_in0 = r0 - HALO;
    load_row(r_in0, stp0, stp1, stg0, stg1);

    // vertical ring: 5 arrays x 11 rows, statically indexed (full unroll)
    float rp[KSIZE], rg[KSIZE], rpp[KSIZE], rgg[KSIZE], rpg[KSIZE];
    float lsum = 0.f;

    const float C1 = 1e-4f;   // 0.01^2
    const float C2 = 9e-4f;   // 0.03^2

    #pragma unroll 1
    for (int ob = 0; ob < 7; ++ob) {
        #pragma unroll
        for (int jj = 0; jj < KSIZE; ++jj) {
            const int i   = ob * KSIZE + jj;   // iteration index 0..76
            const int r   = r_in0 + i;         // input row processed this iter
            const int cur = i & 1;

            // 1) commit staged regs (row r) to buf[cur]
            sp[cur][tid] = stp0;
            sg[cur][tid] = stg0;
            if (has2) { sp[cur][tid + 256] = stp1; sg[cur][tid + 256] = stg1; }

            // 2) issue loads for row r+1 (consumed next iteration)
            load_row(r + 1, stp0, stp1, stg0, stg1);

            // 3) single barrier per row: writes above visible to reads below;
            //    also separates next iter's writes to buf[cur^1] from the
            //    reads of buf[cur^1] two iterations ago.
            __syncthreads();

            // 4) horizontal 11-tap conv at column tid (stride-1 LDS reads)
            float hp = 0.f, hg = 0.f, hpp = 0.f, hgg = 0.f, hpg = 0.f;
            #pragma unroll
            for (int k = 0; k < KSIZE; ++k) {
                float p  = sp[cur][tid + k];
                float g  = sg[cur][tid + k];
                float t1 = wgt[k] * p;
                float t2 = wgt[k] * g;
                hp += t1;
                hg += t2;
                hpp = fmaf(t1, p, hpp);
                hgg = fmaf(t2, g, hgg);
                hpg = fmaf(t1, g, hpg);
            }
            rp[jj] = hp; rg[jj] = hg; rpp[jj] = hpp; rgg[jj] = hgg; rpg[jj] = hpg;

            // 5) vertical conv + SSIM once ring is full (output row o = r-5)
            if (i >= 10 && i < 10 + TH) {
                float mu1 = 0.f, mu2 = 0.f, svpp = 0.f, svgg = 0.f, svpg = 0.f;
                #pragma unroll
                for (int d = 0; d < KSIZE; ++d) {
                    const int slot = (jj + 1 + d) % KSIZE;  // static after unroll
                    const float wv = wgt[d];
                    mu1  = fmaf(wv, rp[slot],  mu1);
                    mu2  = fmaf(wv, rg[slot],  mu2);
                    svpp = fmaf(wv, rpp[slot], svpp);
                    svgg = fmaf(wv, rgg[slot], svgg);
                    svpg = fmaf(wv, rpg[slot], svpg);
                }
                const float m11 = mu1 * mu1;
                const float m22 = mu2 * mu2;
                const float m12 = mu1 * mu2;
                const float s1  = svpp - m11;
                const float s2  = svgg - m22;
                const float s12 = svpg - m12;
                const float num = fmaf(2.f, m12, C1) * fmaf(2.f, s12, C2);
                const float den = (m11 + m22 + C1) * (s1 + s2 + C2);
                lsum += num * __builtin_amdgcn_rcpf(den);
            }
        }
    }

    // block reduction -> one atomic per block
    #pragma unroll
    for (int off = 32; off > 0; off >>= 1) lsum += __shfl_down(lsum, off);
    if ((tid & 63) == 0) wsum[tid >> 6] = lsum;
    __syncthreads();
    if (tid == 0) {
        float b = wsum[0] + wsum[1] + wsum[2] + wsum[3];
        atomicAdd(partial, b);
    }
}

__global__ void ssim_final(const float* __restrict__ partial,
                           float* __restrict__ out) {
    out[0] = 1.f - partial[0] * (1.f / (float)((size_t)NIMG * IMG_H * IMG_W));
}

extern "C" void kernel_launch(void* const* d_in, const int* in_sizes, int n_in,
                              void* d_out, int out_size, void* d_ws, size_t ws_size,
                              hipStream_t stream) {
    const float* pred = (const float*)d_in[0];
    const float* gt   = (const float*)d_in[1];
    float* out = (float*)d_out;
    float* ws  = (float*)d_ws;

    hipMemsetAsync(ws, 0, sizeof(float), stream);

    const int nblocks = NIMG * (IMG_W / TCOLS) * (IMG_H / TH);  // 64*2*8 = 1024
    ssim_main<<<nblocks, 256, 0, stream>>>(pred, gt, ws);
    ssim_final<<<1, 1, 0, stream>>>(ws, out);
}

// Round 2
// 185.267 us; speedup vs baseline: 1.0338x; 1.0338x over previous
//
#include <hip/hip_runtime.h>
#include <math.h>
#include <type_traits>

#define IMG_H 512
#define IMG_W 512
#define NIMG 64
#define TH 64        // output rows per wave tile
#define HALO 5
#define KSIZE 11
#define LROW 74      // 64 output cols + 2*5 halo staged per wave

// 4 independent waves per block; each wave owns a private 64x64 output tile
// and a private LDS row buffer. NO __syncthreads in the hot loop: cross-lane
// halo exchange happens within one wave (in-order DS pipe), guarded by
// __builtin_amdgcn_wave_barrier() scheduling fences. This keeps the row r+1
// global-load prefetch in flight across row boundaries with a counted vmcnt
// instead of the vmcnt(0) drain that s_barrier would force.
__global__ __launch_bounds__(256, 4)
void ssim_main(const float* __restrict__ pred, const float* __restrict__ gt,
               float* __restrict__ partial) {
    __shared__ float sp[4][LROW];
    __shared__ float sg[4][LROW];
    __shared__ float wsum[4];

    const int tid  = threadIdx.x;
    const int wv   = tid >> 6;
    const int lane = tid & 63;
    const int bid  = blockIdx.x;
    const int img  = bid >> 4;          // 16 blocks per image
    const int rem  = bid & 15;
    const int c0   = (rem & 1) * 256 + wv * 64;  // wave's first output col
    const int r0   = (rem >> 1) * TH;            // wave's first output row

    // Gaussian window (sigma = 11/6, normalized) — matches reference.
    float wgt[KSIZE];
    {
        const float sigma = 11.0f / 6.0f;
        float s = 0.f;
        #pragma unroll
        for (int i = 0; i < KSIZE; ++i) {
            float d = (float)(i - 5);
            wgt[i] = expf(-d * d / (2.f * sigma * sigma));
            s += wgt[i];
        }
        float inv = 1.f / s;
        #pragma unroll
        for (int i = 0; i < KSIZE; ++i) wgt[i] *= inv;
    }

    const float* pimg = pred + (size_t)img * IMG_H * IMG_W;
    const float* gimg = gt   + (size_t)img * IMG_H * IMG_W;

    const int  cs0  = c0 - HALO + lane;      // staged col for this lane
    const int  cs1  = cs0 + 64;              // tail col (lanes 0..9)
    const bool has2 = lane < (LROW - 64);
    const bool c0ok = (cs0 >= 0) && (cs0 < IMG_W);
    const bool c1ok = has2 && (cs1 < IMG_W);
    const int  r_in0 = r0 - HALO;
    const int  rtop  = r_in0 + 73;           // last input row actually needed

    float stp0, stp1, stg0, stg1;            // staged regs (next row)
    auto load_row = [&](int rr) {
        const bool rok = (rr >= 0) && (rr < IMG_H) && (rr <= rtop);
        const float* prow = pimg + (size_t)rr * IMG_W;
        const float* grow = gimg + (size_t)rr * IMG_W;
        stp0 = (rok && c0ok) ? prow[cs0] : 0.f;
        stg0 = (rok && c0ok) ? grow[cs0] : 0.f;
        stp1 = (rok && c1ok) ? prow[cs1] : 0.f;
        stg1 = (rok && c1ok) ? grow[cs1] : 0.f;
    };
    load_row(r_in0);

    // vertical ring: 5 arrays x 11 rows, statically indexed (constexpr jj)
    float rp[KSIZE], rg[KSIZE], rpp[KSIZE], rgg[KSIZE], rpg[KSIZE];
    float lsum = 0.f;
    const float C1v = 1e-4f;   // 0.01^2
    const float C2v = 9e-4f;   // 0.03^2

    float* swp = &sp[wv][0];
    float* swg = &sg[wv][0];

    auto step = [&](int i, auto jc) {
        constexpr int jj = decltype(jc)::value;   // ring slot, static
        const int r = r_in0 + i;

        // fence: previous row's LDS reads stay before this row's writes
        __builtin_amdgcn_wave_barrier();

        // 1) commit staged regs (row r) to this wave's LDS row
        swp[lane] = stp0;
        swg[lane] = stg0;
        if (has2) { swp[lane + 64] = stp1; swg[lane + 64] = stg1; }

        // 2) issue loads for row r+1 (stay in flight through this row's compute)
        load_row(r + 1);

        // fence: this row's writes stay before this row's reads
        __builtin_amdgcn_wave_barrier();

        // 3) horizontal 11-tap conv at column c0+lane
        float hp = 0.f, hg = 0.f, hpp = 0.f, hgg = 0.f, hpg = 0.f;
        #pragma unroll
        for (int k = 0; k < KSIZE; ++k) {
            float p  = swp[lane + k];
            float g  = swg[lane + k];
            float t1 = wgt[k] * p;
            float t2 = wgt[k] * g;
            hp += t1;
            hg += t2;
            hpp = fmaf(t1, p, hpp);
            hgg = fmaf(t2, g, hgg);
            hpg = fmaf(t1, g, hpg);
        }
        rp[jj] = hp; rg[jj] = hg; rpp[jj] = hpp; rgg[jj] = hgg; rpg[jj] = hpg;

        // 4) vertical conv + SSIM once ring is full (output row = r-5)
        if (i >= 10 && i < 10 + TH) {
            float mu1 = 0.f, mu2 = 0.f, svpp = 0.f, svgg = 0.f, svpg = 0.f;
            #pragma unroll
            for (int d = 0; d < KSIZE; ++d) {
                const int slot = (jj + 1 + d) % KSIZE;  // constant-folded
                const float wv2 = wgt[d];
                mu1  = fmaf(wv2, rp[slot],  mu1);
                mu2  = fmaf(wv2, rg[slot],  mu2);
                svpp = fmaf(wv2, rpp[slot], svpp);
                svgg = fmaf(wv2, rgg[slot], svgg);
                svpg = fmaf(wv2, rpg[slot], svpg);
            }
            const float m11 = mu1 * mu1;
            const float m22 = mu2 * mu2;
            const float m12 = mu1 * mu2;
            const float s1  = svpp - m11;
            const float s2  = svgg - m22;
            const float s12 = svpg - m12;
            const float num = fmaf(2.f, m12, C1v) * fmaf(2.f, s12, C2v);
            const float den = (m11 + m22 + C1v) * (s1 + s2 + C2v);
            lsum += num * __builtin_amdgcn_rcpf(den);
        }
    };

    #pragma unroll 1
    for (int ob = 0; ob < 7; ++ob) {
        const int base = ob * KSIZE;
        step(base + 0,  std::integral_constant<int, 0>{});
        step(base + 1,  std::integral_constant<int, 1>{});
        step(base + 2,  std::integral_constant<int, 2>{});
        step(base + 3,  std::integral_constant<int, 3>{});
        step(base + 4,  std::integral_constant<int, 4>{});
        step(base + 5,  std::integral_constant<int, 5>{});
        step(base + 6,  std::integral_constant<int, 6>{});
        step(base + 7,  std::integral_constant<int, 7>{});
        step(base + 8,  std::integral_constant<int, 8>{});
        step(base + 9,  std::integral_constant<int, 9>{});
        step(base + 10, std::integral_constant<int, 10>{});
    }

    // per-wave shuffle reduction, then one barrier (outside hot loop) + one
    // atomic per block
    #pragma unroll
    for (int off = 32; off > 0; off >>= 1) lsum += __shfl_down(lsum, off);
    if (lane == 0) wsum[wv] = lsum;
    __syncthreads();
    if (tid == 0) {
        float b = wsum[0] + wsum[1] + wsum[2] + wsum[3];
        atomicAdd(partial, b);
    }
}

__global__ void ssim_final(const float* __restrict__ partial,
                           float* __restrict__ out) {
    out[0] = 1.f - partial[0] * (1.f / (float)((size_t)NIMG * IMG_H * IMG_W));
}

extern "C" void kernel_launch(void* const* d_in, const int* in_sizes, int n_in,
                              void* d_out, int out_size, void* d_ws, size_t ws_size,
                              hipStream_t stream) {
    const float* pred = (const float*)d_in[0];
    const float* gt   = (const float*)d_in[1];
    float* out = (float*)d_out;
    float* ws  = (float*)d_ws;

    hipMemsetAsync(ws, 0, sizeof(float), stream);

    const int nblocks = NIMG * 16;   // 64 imgs * (2 col strips) * (8 row chunks)
    ssim_main<<<nblocks, 256, 0, stream>>>(pred, gt, ws);
    ssim_final<<<1, 1, 0, stream>>>(ws, out);
}